// Round 7
// baseline (490.330 us; speedup 1.0000x reference)
//
#include <hip/hip_runtime.h>
#include <math.h>

#define N_NODES 100000
#define N_EDGES 3200000
#define N_GRAPHS 64
#define IN_DIM 128
#define HID 64
#define BN_EPS 1e-5f

#define PSHIFT 9
#define PBS 512
#define NPB ((N_NODES + PBS - 1) / PBS)  // 196
#define PART_BLOCKS 256
#define CHUNK_E (N_EDGES / PART_BLOCKS)  // 12500 (multiple of 4)

#define QBOUND 25000
#define NB_AGG ((N_NODES + 63) / 64)  // 1563: 16 groups/block x 4 nodes/group
#define SENT_OFF (N_NODES << 7)       // byte offset of zeroed sentinel row in hs

typedef unsigned short ushort_t;
typedef __attribute__((ext_vector_type(8))) short bf16x8;
typedef __attribute__((ext_vector_type(4))) float f32x4;

__device__ __forceinline__ float bflo(unsigned u) { return __uint_as_float(u << 16); }
__device__ __forceinline__ float bfhi(unsigned u) { return __uint_as_float(u & 0xFFFF0000u); }
__device__ __forceinline__ float bfu(ushort_t u) { return __uint_as_float((unsigned)u << 16); }
__device__ __forceinline__ unsigned f2bf(float f) {  // RNE
  unsigned u = __float_as_uint(f);
  return (u + 0x7FFFu + ((u >> 16) & 1u)) >> 16;
}

// ---------------- CSR build: two-level bucket sort, int4-vectorized ----------------
// Quartile sub-sort retained: agg no longer phases, but src-ascending order
// within each node's run improves gather L2 locality for free.

__global__ __launch_bounds__(256) void ghist_k(const int* __restrict__ ei,
                                               int* __restrict__ gh) {
  __shared__ int h[NPB];
  for (int i = threadIdx.x; i < NPB; i += 256) h[i] = 0;
  __syncthreads();
  const int4* d4 = (const int4*)(ei + N_EDGES);
  int n4 = N_EDGES / 4;
  int stride = gridDim.x * 256;
  for (int i = blockIdx.x * 256 + threadIdx.x; i < n4; i += stride) {
    int4 d = d4[i];
    atomicAdd(&h[d.x >> PSHIFT], 1);
    atomicAdd(&h[d.y >> PSHIFT], 1);
    atomicAdd(&h[d.z >> PSHIFT], 1);
    atomicAdd(&h[d.w >> PSHIFT], 1);
  }
  __syncthreads();
  for (int i = threadIdx.x; i < NPB; i += 256) {
    int v = h[i];
    if (v) atomicAdd(&gh[i], v);
  }
}

__global__ __launch_bounds__(256) void gscan_k(const int* __restrict__ gh,
                                               int* __restrict__ boff,
                                               int* __restrict__ gcur) {
  __shared__ int sa[256], sb[256];
  int t = threadIdx.x;
  int v = (t < NPB) ? gh[t] : 0;
  sa[t] = v;
  __syncthreads();
  int* src = sa; int* dst = sb;
  for (int o = 1; o < 256; o <<= 1) {
    dst[t] = src[t] + ((t >= o) ? src[t - o] : 0);
    __syncthreads();
    int* tmp = src; src = dst; dst = tmp;
  }
  if (t < NPB) {
    int excl = src[t] - v;
    boff[t] = excl;
    gcur[t] = excl;
    if (t == NPB - 1) boff[NPB] = src[t];
  }
}

__global__ __launch_bounds__(512) void part_k(const int* __restrict__ ei,
                                              int* __restrict__ gcur,
                                              unsigned* __restrict__ tmp) {
  __shared__ int lh[NPB];
  __shared__ int lcur[NPB];
  int t = threadIdx.x;
  for (int i = t; i < NPB; i += 512) lh[i] = 0;
  __syncthreads();
  int q0 = blockIdx.x * (CHUNK_E / 4);
  int q1 = q0 + CHUNK_E / 4;
  const int4* d4 = (const int4*)(ei + N_EDGES);
  const int4* s4 = (const int4*)ei;
  for (int i = q0 + t; i < q1; i += 512) {
    int4 d = d4[i];
    atomicAdd(&lh[d.x >> PSHIFT], 1);
    atomicAdd(&lh[d.y >> PSHIFT], 1);
    atomicAdd(&lh[d.z >> PSHIFT], 1);
    atomicAdd(&lh[d.w >> PSHIFT], 1);
  }
  __syncthreads();
  for (int i = t; i < NPB; i += 512) {
    int v = lh[i];
    lcur[i] = v ? atomicAdd(&gcur[i], v) : 0;
  }
  __syncthreads();
  for (int i = q0 + t; i < q1; i += 512) {
    int4 d = d4[i];
    int4 s = s4[i];
    int b0 = d.x >> PSHIFT, b1 = d.y >> PSHIFT, b2 = d.z >> PSHIFT, b3 = d.w >> PSHIFT;
    int p0 = atomicAdd(&lcur[b0], 1);
    int p1 = atomicAdd(&lcur[b1], 1);
    int p2 = atomicAdd(&lcur[b2], 1);
    int p3 = atomicAdd(&lcur[b3], 1);
    tmp[p0] = ((unsigned)(d.x & (PBS - 1)) << 17) | (unsigned)s.x;
    tmp[p1] = ((unsigned)(d.y & (PBS - 1)) << 17) | (unsigned)s.y;
    tmp[p2] = ((unsigned)(d.z & (PBS - 1)) << 17) | (unsigned)s.z;
    tmp[p3] = ((unsigned)(d.w & (PBS - 1)) << 17) | (unsigned)s.w;
  }
}

// fused per-bucket: histogram per (node, src-quartile) -> rp4/dinv -> place
__global__ __launch_bounds__(512) void bwork_k(
    const unsigned* __restrict__ tmp, const int* __restrict__ boff,
    int* __restrict__ rp4, float* __restrict__ dinv, int* __restrict__ csr) {
  int b = blockIdx.x;
  int base = boff[b], end = boff[b + 1];
  int t = threadIdx.x;
  __shared__ int cnt[PBS * 4];
  __shared__ int cur[PBS * 4];
  __shared__ int sa[PBS], sb[PBS];
  for (int i = t; i < PBS * 4; i += 512) cnt[i] = 0;
  __syncthreads();
  int a0 = (base + 3) & ~3;
  int a1 = end & ~3;
  if (a1 < a0) { a0 = end; a1 = end; }
  const uint4* t4 = (const uint4*)tmp;
#define HIST1(U) { unsigned u_ = (U); int nl_ = u_ >> 17; int s_ = u_ & 0x1FFFF; \
    int qq_ = (s_ >= QBOUND) + (s_ >= 2*QBOUND) + (s_ >= 3*QBOUND); \
    atomicAdd(&cnt[nl_ * 4 + qq_], 1); }
  if (base + t < a0) HIST1(tmp[base + t]);
  for (int i = a0 / 4 + t; i < a1 / 4; i += 512) {
    uint4 u = t4[i];
    HIST1(u.x) HIST1(u.y) HIST1(u.z) HIST1(u.w)
  }
  if (a1 + t < end) HIST1(tmp[a1 + t]);
#undef HIST1
  __syncthreads();
  int c0 = cnt[t * 4], c1 = cnt[t * 4 + 1], c2 = cnt[t * 4 + 2], c3 = cnt[t * 4 + 3];
  int tsum = c0 + c1 + c2 + c3;
  sa[t] = tsum;
  __syncthreads();
  int* src_ = sa; int* dst_ = sb;
  for (int o = 1; o < PBS; o <<= 1) {
    dst_[t] = src_[t] + ((t >= o) ? src_[t - o] : 0);
    __syncthreads();
    int* z = src_; src_ = dst_; dst_ = z;
  }
  int nb = src_[t] - tsum;
  int o0 = nb, o1 = nb + c0, o2 = nb + c0 + c1, o3 = nb + c0 + c1 + c2;
  cur[t * 4] = o0; cur[t * 4 + 1] = o1; cur[t * 4 + 2] = o2; cur[t * 4 + 3] = o3;
  int n = b * PBS + t;
  if (n < N_NODES) {
    rp4[4 * n] = base + o0;
    rp4[4 * n + 1] = base + o1;
    rp4[4 * n + 2] = base + o2;
    rp4[4 * n + 3] = base + o3;
    dinv[n] = rsqrtf((float)(tsum + 1));  // +1 self loop
    if (n == N_NODES - 1) rp4[4 * N_NODES] = base + nb + tsum;
  }
  __syncthreads();
#define PLACE1(U) { unsigned u_ = (U); int nl_ = u_ >> 17; int s_ = u_ & 0x1FFFF; \
    int qq_ = (s_ >= QBOUND) + (s_ >= 2*QBOUND) + (s_ >= 3*QBOUND); \
    int p_ = atomicAdd(&cur[nl_ * 4 + qq_], 1); \
    csr[base + p_] = s_ << 7; }
  if (base + t < a0) PLACE1(tmp[base + t]);
  for (int i = a0 / 4 + t; i < a1 / 4; i += 512) {
    uint4 u = t4[i];
    PLACE1(u.x) PLACE1(u.y) PLACE1(u.z) PLACE1(u.w)
  }
  if (a1 + t < end) PLACE1(tmp[a1 + t]);
#undef PLACE1
}

// ---------------- MFMA GEMM: hs[n][c] = dinv[n] * (BN(X)[n] @ W)[c] -> bf16 ----------------

template <int K, bool XBF16, bool APPLY, bool RELU>
__global__ __launch_bounds__(256) void gemm_k(
    const void* __restrict__ Xv, const float* __restrict__ W,
    const float* __restrict__ sums, const float* __restrict__ gamma,
    const float* __restrict__ beta, const float* __restrict__ dinv,
    ushort_t* __restrict__ out, int nrows) {
  __shared__ ushort_t wt[64 * K];   // wt[n][k] bf16
  __shared__ float scs[128], shs[128];
  __shared__ float redo[64 * 65];   // D repack, padded
  const int tid = threadIdx.x;
  const int wv = tid >> 6;
  const int lane = tid & 63;
  const int lm = lane & 15;
  const int lq = lane >> 4;

  for (int idx = tid; idx < K * 64; idx += 256) {
    int k = idx >> 6, c = idx & 63;      // W[k][c]
    wt[c * K + k] = (ushort_t)f2bf(W[idx]);
  }
  if (APPLY) {
    for (int k = tid; k < K; k += 256) {
      float m = sums[k] / (float)N_NODES;
      float v = sums[64 + k] / (float)N_NODES - m * m;
      float s = gamma[k] * rsqrtf(v + BN_EPS);
      scs[k] = s;
      shs[k] = beta[k] - m * s;
    }
  }
  __syncthreads();

  const int rowbase = blockIdx.x * 64;
  const int grow = rowbase + wv * 16 + lm;
  const bool valid = grow < nrows;
  f32x4 acc0 = {0.f, 0.f, 0.f, 0.f};
  f32x4 acc1 = acc0, acc2 = acc0, acc3 = acc0;

#pragma unroll
  for (int k0 = 0; k0 < K; k0 += 32) {
    int kbase = k0 + lq * 8;
    bf16x8 a = {0, 0, 0, 0, 0, 0, 0, 0};
    if (valid) {
      if (XBF16) {
        uint4 u = *(const uint4*)((const char*)Xv + ((size_t)grow * 64 + kbase) * 2);
        if (APPLY) {
          float4 sc0 = *(const float4*)&scs[kbase];
          float4 sc1 = *(const float4*)&scs[kbase + 4];
          float4 sh0 = *(const float4*)&shs[kbase];
          float4 sh1 = *(const float4*)&shs[kbase + 4];
          float f0 = bflo(u.x) * sc0.x + sh0.x, f1 = bfhi(u.x) * sc0.y + sh0.y;
          float f2 = bflo(u.y) * sc0.z + sh0.z, f3 = bfhi(u.y) * sc0.w + sh0.w;
          float f4 = bflo(u.z) * sc1.x + sh1.x, f5 = bfhi(u.z) * sc1.y + sh1.y;
          float f6 = bflo(u.w) * sc1.z + sh1.z, f7 = bfhi(u.w) * sc1.w + sh1.w;
          if (RELU) {
            f0 = fmaxf(f0, 0.f); f1 = fmaxf(f1, 0.f);
            f2 = fmaxf(f2, 0.f); f3 = fmaxf(f3, 0.f);
            f4 = fmaxf(f4, 0.f); f5 = fmaxf(f5, 0.f);
            f6 = fmaxf(f6, 0.f); f7 = fmaxf(f7, 0.f);
          }
          a[0] = (short)f2bf(f0); a[1] = (short)f2bf(f1);
          a[2] = (short)f2bf(f2); a[3] = (short)f2bf(f3);
          a[4] = (short)f2bf(f4); a[5] = (short)f2bf(f5);
          a[6] = (short)f2bf(f6); a[7] = (short)f2bf(f7);
        } else {
          a = *(const bf16x8*)&u;
        }
      } else {
        const float* xp = (const float*)Xv + (size_t)grow * K + kbase;
        float4 xa = *(const float4*)xp;
        float4 xb = *(const float4*)(xp + 4);
        a[0] = (short)f2bf(xa.x); a[1] = (short)f2bf(xa.y);
        a[2] = (short)f2bf(xa.z); a[3] = (short)f2bf(xa.w);
        a[4] = (short)f2bf(xb.x); a[5] = (short)f2bf(xb.y);
        a[6] = (short)f2bf(xb.z); a[7] = (short)f2bf(xb.w);
      }
    }
    bf16x8 b0 = *(const bf16x8*)(wt + (0 + lm) * K + kbase);
    bf16x8 b1 = *(const bf16x8*)(wt + (16 + lm) * K + kbase);
    bf16x8 b2 = *(const bf16x8*)(wt + (32 + lm) * K + kbase);
    bf16x8 b3 = *(const bf16x8*)(wt + (48 + lm) * K + kbase);
    acc0 = __builtin_amdgcn_mfma_f32_16x16x32_bf16(a, b0, acc0, 0, 0, 0);
    acc1 = __builtin_amdgcn_mfma_f32_16x16x32_bf16(a, b1, acc1, 0, 0, 0);
    acc2 = __builtin_amdgcn_mfma_f32_16x16x32_bf16(a, b2, acc2, 0, 0, 0);
    acc3 = __builtin_amdgcn_mfma_f32_16x16x32_bf16(a, b3, acc3, 0, 0, 0);
  }

#pragma unroll
  for (int r = 0; r < 4; ++r) {
    int rr = wv * 16 + lq * 4 + r;
    redo[rr * 65 + lm] = acc0[r];
    redo[rr * 65 + 16 + lm] = acc1[r];
    redo[rr * 65 + 32 + lm] = acc2[r];
    redo[rr * 65 + 48 + lm] = acc3[r];
  }
  __syncthreads();
  {
    int r = tid >> 2;
    int cq = (tid & 3) * 16;
    int gr = rowbase + r;
    if (gr < nrows) {
      float dn = dinv[gr];
      const float* sp = &redo[r * 65 + cq];
      unsigned p[8];
#pragma unroll
      for (int i = 0; i < 8; ++i)
        p[i] = f2bf(sp[2 * i] * dn) | (f2bf(sp[2 * i + 1] * dn) << 16);
      char* ob = (char*)out + ((size_t)gr * 64 + cq) * 2;
      *(uint4*)ob = make_uint4(p[0], p[1], p[2], p[3]);
      *(uint4*)(ob + 16) = make_uint4(p[4], p[5], p[6], p[7]);
    }
  }
}

// ---------------- aggregation: UNPHASED, 16-lane x uint2 rows, 4-node interleave, depth-8 ----------------
// Final agg form from the r0-r6 study: time is set by distinct-64B-line gather
// service (~4.5 TB/s); granularity evidence says 4-rows-per-instruction (uint2,
// 16 lanes/row) beats 8-rows-per-instruction (r4/r6). Quartile phasing bought
// FETCH reduction but zero time (r0 87.8 == r3 88.4) while costing ~1.6x dead
// slots on short segments -> removed: each node processes its FULL run
// [rp4[4n], rp4[4n+4]) (mean 32 edges, ~1.3x slots at lookahead 2/node). The
// quartile-sorted CSR now just provides src-ascending order (L2 locality).
// Sentinel row absorbs tail slots (exact +0.0). POOL=true (layer 3): skip the
// out-write, fuse raw graph pooling via block LDS; BN3 affine in classify_k.

template <bool POOL>
__global__ __launch_bounds__(256) void agg_k(
    const ushort_t* __restrict__ hs, const float* __restrict__ dinv,
    const int* __restrict__ rp4, const int* __restrict__ csr,
    const float* __restrict__ bias, ushort_t* __restrict__ out,
    float* __restrict__ sums, const int* __restrict__ batch,
    float* __restrict__ psum, float* __restrict__ pcnt) {
  const int tid = threadIdx.x;
  const int w = tid >> 6;
  const int lane = tid & 63;
  const int g = lane >> 4;     // node-group slot within wave
  const int q = lane & 15;     // feature quad
  const char* hb = (const char*)hs;
  char* ob = (char*)out;
  const int qo = q << 3;

  __shared__ float rs[16][64];
  __shared__ float rs2[16][64];
  __shared__ float pl[POOL ? 64 * 64 : 1];
  __shared__ float pcl[POOL ? 64 : 1];
  if (POOL) {
    for (int i = tid; i < 64 * 64; i += 256) pl[i] = 0.f;
    if (tid < 64) pcl[tid] = 0.f;
    __syncthreads();
  }

  const int nb = blockIdx.x * 64 + (w * 4 + g) * 4;  // first of 4 nodes

  int j0 = 0, h0 = 0, j1 = 0, h1 = 0, j2 = 0, h2 = 0, j3 = 0, h3 = 0;
  if (nb < N_NODES)     { j0 = rp4[4 * nb];           h0 = rp4[4 * nb + 4]; }
  if (nb + 1 < N_NODES) { j1 = rp4[4 * (nb + 1)];     h1 = rp4[4 * (nb + 1) + 4]; }
  if (nb + 2 < N_NODES) { j2 = rp4[4 * (nb + 2)];     h2 = rp4[4 * (nb + 2) + 4]; }
  if (nb + 3 < N_NODES) { j3 = rp4[4 * (nb + 3)];     h3 = rp4[4 * (nb + 3) + 4]; }

  float4 bval = *(const float4*)(bias + q * 4);
  float4 acc0 = make_float4(0.f, 0.f, 0.f, 0.f);
  float4 acc1 = acc0, acc2 = acc0, acc3 = acc0;

#define ACCV(A, V) { \
    A.x += bflo((V).x); A.y += bfhi((V).x); A.z += bflo((V).y); A.w += bfhi((V).y); }
// sentinel-selected csr fetch: in-bounds -> csr[j]; OOB -> zeroed row offset
#define EFETCH(J, H) ((J) < (H) ? csr[(J)] : (int)SENT_OFF)

  {
    int mrem = max(max(h0 - j0, h1 - j1), max(h2 - j2, h3 - j3));
    int iters = (mrem + 1) >> 1;
    if (iters > 0) {
      // prologue: first csr batch (OOB slots -> sentinel row)
      int e00 = EFETCH(j0, h0);
      int e01 = EFETCH(j0 + 1, h0);
      int e10 = EFETCH(j1, h1);
      int e11 = EFETCH(j1 + 1, h1);
      int e20 = EFETCH(j2, h2);
      int e21 = EFETCH(j2 + 1, h2);
      int e30 = EFETCH(j3, h3);
      int e31 = EFETCH(j3 + 1, h3);
      for (int it = 0; it < iters; ++it) {
        // 8 gathers in flight, 4 rows x 128 B per instruction
        uint2 v00 = *(const uint2*)(hb + (size_t)(unsigned)e00 + qo);
        uint2 v01 = *(const uint2*)(hb + (size_t)(unsigned)e01 + qo);
        uint2 v10 = *(const uint2*)(hb + (size_t)(unsigned)e10 + qo);
        uint2 v11 = *(const uint2*)(hb + (size_t)(unsigned)e11 + qo);
        uint2 v20 = *(const uint2*)(hb + (size_t)(unsigned)e20 + qo);
        uint2 v21 = *(const uint2*)(hb + (size_t)(unsigned)e21 + qo);
        uint2 v30 = *(const uint2*)(hb + (size_t)(unsigned)e30 + qo);
        uint2 v31 = *(const uint2*)(hb + (size_t)(unsigned)e31 + qo);
        j0 += 2; j1 += 2; j2 += 2; j3 += 2;
        // prefetch next csr batch while gathers are in flight
        e00 = EFETCH(j0, h0);
        e01 = EFETCH(j0 + 1, h0);
        e10 = EFETCH(j1, h1);
        e11 = EFETCH(j1 + 1, h1);
        e20 = EFETCH(j2, h2);
        e21 = EFETCH(j2 + 1, h2);
        e30 = EFETCH(j3, h3);
        e31 = EFETCH(j3 + 1, h3);
        // accumulate (sentinel contributes exact +0.0)
        ACCV(acc0, v00) ACCV(acc0, v01)
        ACCV(acc1, v10) ACCV(acc1, v11)
        ACCV(acc2, v20) ACCV(acc2, v21)
        ACCV(acc3, v30) ACCV(acc3, v31)
      }
    }
  }
#undef ACCV
#undef EFETCH

  float4 s = make_float4(0.f, 0.f, 0.f, 0.f);
  float4 s2 = make_float4(0.f, 0.f, 0.f, 0.f);
  int curg = -1, pcount = 0;
  float4 pacc = make_float4(0.f, 0.f, 0.f, 0.f);
#pragma unroll
  for (int i = 0; i < 4; ++i) {
    int n = nb + i;
    if (n < N_NODES) {
      float4 ai = (i == 0) ? acc0 : (i == 1) ? acc1 : (i == 2) ? acc2 : acc3;
      uint2 su = *(const uint2*)(hb + ((size_t)n << 7) + qo);
      float dn = dinv[n];
      float4 a;
      a.x = (ai.x + bflo(su.x)) * dn + bval.x;
      a.y = (ai.y + bfhi(su.x)) * dn + bval.y;
      a.z = (ai.z + bflo(su.y)) * dn + bval.z;
      a.w = (ai.w + bfhi(su.y)) * dn + bval.w;
      if (!POOL) {
        uint2 o;
        o.x = f2bf(a.x) | (f2bf(a.y) << 16);
        o.y = f2bf(a.z) | (f2bf(a.w) << 16);
        *(uint2*)(ob + ((size_t)n << 7) + qo) = o;
      } else {
        int gi = batch[n];  // uniform across the 16-lane group
        if (gi != curg) {
          if (pcount) {
            atomicAdd(&pl[curg * 64 + (q << 2)], pacc.x);
            atomicAdd(&pl[curg * 64 + (q << 2) + 1], pacc.y);
            atomicAdd(&pl[curg * 64 + (q << 2) + 2], pacc.z);
            atomicAdd(&pl[curg * 64 + (q << 2) + 3], pacc.w);
            if (q == 0) atomicAdd(&pcl[curg], (float)pcount);
          }
          curg = gi;
          pacc = a;
          pcount = 1;
        } else {
          pacc.x += a.x; pacc.y += a.y; pacc.z += a.z; pacc.w += a.w;
          pcount++;
        }
      }
      s.x += a.x; s.y += a.y; s.z += a.z; s.w += a.w;
      s2.x += a.x * a.x; s2.y += a.y * a.y;
      s2.z += a.z * a.z; s2.w += a.w * a.w;
    }
  }
  if (POOL && pcount) {
    atomicAdd(&pl[curg * 64 + (q << 2)], pacc.x);
    atomicAdd(&pl[curg * 64 + (q << 2) + 1], pacc.y);
    atomicAdd(&pl[curg * 64 + (q << 2) + 2], pacc.z);
    atomicAdd(&pl[curg * 64 + (q << 2) + 3], pacc.w);
    if (q == 0) atomicAdd(&pcl[curg], (float)pcount);
  }

  *(float4*)(&rs[w * 4 + g][q * 4]) = s;
  *(float4*)(&rs2[w * 4 + g][q * 4]) = s2;
  __syncthreads();
  int c = tid & 63;
  int r0_ = tid >> 6;
  float a = rs[r0_][c] + rs[r0_ + 4][c] + rs[r0_ + 8][c] + rs[r0_ + 12][c];
  float a2 = rs2[r0_][c] + rs2[r0_ + 4][c] + rs2[r0_ + 8][c] + rs2[r0_ + 12][c];
  __syncthreads();
  rs[r0_][c] = a;
  rs2[r0_][c] = a2;
  __syncthreads();
  if (r0_ == 0) {
    atomicAdd(&sums[c], rs[0][c] + rs[1][c] + rs[2][c] + rs[3][c]);
    atomicAdd(&sums[64 + c], rs2[0][c] + rs2[1][c] + rs2[2][c] + rs2[3][c]);
  }
  if (POOL) {
    for (int idx = tid; idx < 64 * 64; idx += 256) {
      int gi = idx >> 6;
      if (pcl[gi] != 0.f) atomicAdd(&psum[idx], pl[idx]);
    }
    if (tid < 64 && pcl[tid] != 0.f) atomicAdd(&pcnt[tid], pcl[tid]);
  }
}

// ---------------- centroid classifier (BN3 affine applied here) ----------------

__global__ void classify_k(const float* __restrict__ psum, const float* __restrict__ pcnt,
                           const float* __restrict__ sums, const float* __restrict__ gamma,
                           const float* __restrict__ beta,
                           const float* __restrict__ cg_, const float* __restrict__ cm,
                           const float* __restrict__ temp, float* __restrict__ out) {
  int g = blockIdx.x;
  int t = threadIdx.x;
  __shared__ float emb[64];
  __shared__ float dist[208];
  if (t < 64) {
    float m = sums[t] / (float)N_NODES;
    float v = sums[64 + t] / (float)N_NODES - m * m;
    float sc = gamma[t] * rsqrtf(v + BN_EPS);
    float sh = beta[t] - m * sc;
    // mean(BN(a)) = sc*mean(a) + sh  (affine commutes with the mean)
    emb[t] = psum[g * 64 + t] / fmaxf(pcnt[g], 1.0f) * sc + sh;
  }
  __syncthreads();
  if (t < 197) {
    const float* C = (t < 5) ? (cg_ + t * 64) : (cm + (t - 5) * 64);
    float d = 0.f;
#pragma unroll 8
    for (int k = 0; k < 64; ++k) {
      float df = emb[k] - C[k];
      d += df * df;
    }
    dist[t] = d;
  }
  __syncthreads();
  float tv = temp[0];
  if (t == 64) {
    float m = dist[0];
    for (int j = 1; j < 5; ++j) m = fminf(m, dist[j]);
    out[g * 65] = -m / tv;
  }
  if (t < 64) {
    float m = fminf(dist[5 + t * 3], fminf(dist[5 + t * 3 + 1], dist[5 + t * 3 + 2]));
    out[g * 65 + 1 + t] = -m / tv;
  }
}

// ---------------- launch ----------------

extern "C" void kernel_launch(void* const* d_in, const int* in_sizes, int n_in,
                              void* d_out, int out_size, void* d_ws, size_t ws_size,
                              hipStream_t stream) {
  const float* x   = (const float*)d_in[0];
  const int* ei    = (const int*)d_in[1];
  const int* batch = (const int*)d_in[2];
  const float* W1 = (const float*)d_in[3];  const float* b1 = (const float*)d_in[4];
  const float* g1 = (const float*)d_in[5];  const float* be1 = (const float*)d_in[6];
  const float* W2 = (const float*)d_in[7];  const float* b2 = (const float*)d_in[8];
  const float* g2 = (const float*)d_in[9];  const float* be2 = (const float*)d_in[10];
  const float* W3 = (const float*)d_in[11]; const float* b3 = (const float*)d_in[12];
  const float* g3 = (const float*)d_in[13]; const float* be3 = (const float*)d_in[14];
  const float* cg_ = (const float*)d_in[15];
  const float* cm = (const float*)d_in[16];
  const float* temp = (const float*)d_in[17];
  float* out = (float*)d_out;

  char* ws = (char*)d_ws;
  size_t off = 0;
  auto alloc = [&](size_t bytes) -> void* {
    void* p = ws + off;
    off = (off + bytes + 255) & ~(size_t)255;
    return p;
  };
  // zero-init block first -> single memset
  int* gh        = (int*)alloc((size_t)NPB * 4);
  float* sumsAll = (float*)alloc(3 * 128 * 4);
  float* psum    = (float*)alloc(64 * 64 * 4);
  float* pcnt    = (float*)alloc(64 * 4);
  size_t zero_end = off;
  int* boff      = (int*)alloc((size_t)(NPB + 1) * 4);
  int* gcur      = (int*)alloc((size_t)NPB * 4);
  unsigned* tmp  = (unsigned*)alloc((size_t)N_EDGES * 4);
  int* csr       = (int*)alloc((size_t)N_EDGES * 4);
  int* rp4       = (int*)alloc((size_t)(4 * N_NODES + 1) * 4);
  float* dinv    = (float*)alloc((size_t)N_NODES * 4);
  ushort_t* hA   = (ushort_t*)alloc((size_t)(N_NODES + 1) * 64 * 2);  // bf16 hs + sentinel row
  ushort_t* hB   = (ushort_t*)alloc((size_t)N_NODES * 64 * 2);        // bf16 h (pre-BN)

  hipMemsetAsync(ws, 0, zero_end, stream);
  hipMemsetAsync(hA + (size_t)N_NODES * 64, 0, 128, stream);  // zero sentinel row

  const int NB_GEMM = (N_NODES + 63) / 64;   // 1563

  // CSR build
  ghist_k<<<512, 256, 0, stream>>>(ei, gh);
  gscan_k<<<1, 256, 0, stream>>>(gh, boff, gcur);
  part_k<<<PART_BLOCKS, 512, 0, stream>>>(ei, gcur, tmp);
  bwork_k<<<NPB, 512, 0, stream>>>(tmp, boff, rp4, dinv, csr);

  // layer 1 (MFMA, fp32 X -> bf16 frags)
  gemm_k<IN_DIM, false, false, false><<<NB_GEMM, 256, 0, stream>>>(x, W1, nullptr, nullptr, nullptr, dinv, hA, N_NODES);
  agg_k<false><<<NB_AGG, 256, 0, stream>>>(hA, dinv, rp4, csr, b1, hB, sumsAll, nullptr, nullptr, nullptr);

  // layer 2 (BN1+ReLU inline from sums, bf16 input)
  gemm_k<HID, true, true, true><<<NB_GEMM, 256, 0, stream>>>(hB, W2, sumsAll, g1, be1, dinv, hA, N_NODES);
  agg_k<false><<<NB_AGG, 256, 0, stream>>>(hA, dinv, rp4, csr, b2, hB, sumsAll + 128, nullptr, nullptr, nullptr);

  // layer 3 (BN2+ReLU inline from sums, bf16 input); agg fuses raw pooling
  gemm_k<HID, true, true, true><<<NB_GEMM, 256, 0, stream>>>(hB, W3, sumsAll + 128, g2, be2, dinv, hA, N_NODES);
  agg_k<true><<<NB_AGG, 256, 0, stream>>>(hA, dinv, rp4, csr, b3, nullptr, sumsAll + 256, batch, psum, pcnt);

  // classify (BN3 affine inline from sums)
  classify_k<<<N_GRAPHS, 256, 0, stream>>>(psum, pcnt, sumsAll + 256, g3, be3, cg_, cm, temp, out);
}

// Round 8
// 481.215 us; speedup vs baseline: 1.0189x; 1.0189x over previous
//
#include <hip/hip_runtime.h>
#include <math.h>

#define N_NODES 100000
#define N_EDGES 3200000
#define N_GRAPHS 64
#define IN_DIM 128
#define HID 64
#define BN_EPS 1e-5f

#define PSHIFT 9
#define PBS 512
#define NPB ((N_NODES + PBS - 1) / PBS)  // 196
#define PART_BLOCKS 256
#define CHUNK_E (N_EDGES / PART_BLOCKS)  // 12500 (multiple of 4)

#define QBOUND 25000
#define NB_AGG ((N_NODES + 63) / 64)  // 1563: 16 groups/block x 4 nodes/group
#define SENT_OFF (N_NODES << 7)       // byte offset of zeroed sentinel row in hs

typedef unsigned short ushort_t;
typedef __attribute__((ext_vector_type(8))) short bf16x8;
typedef __attribute__((ext_vector_type(4))) float f32x4;

__device__ __forceinline__ float bflo(unsigned u) { return __uint_as_float(u << 16); }
__device__ __forceinline__ float bfhi(unsigned u) { return __uint_as_float(u & 0xFFFF0000u); }
__device__ __forceinline__ float bfu(ushort_t u) { return __uint_as_float((unsigned)u << 16); }
__device__ __forceinline__ unsigned f2bf(float f) {  // RNE
  unsigned u = __float_as_uint(f);
  return (u + 0x7FFFu + ((u >> 16) & 1u)) >> 16;
}

// ---------------- CSR build: two-level bucket sort, int4-vectorized ----------------

__global__ __launch_bounds__(256) void ghist_k(const int* __restrict__ ei,
                                               int* __restrict__ gh) {
  __shared__ int h[NPB];
  for (int i = threadIdx.x; i < NPB; i += 256) h[i] = 0;
  __syncthreads();
  const int4* d4 = (const int4*)(ei + N_EDGES);
  int n4 = N_EDGES / 4;
  int stride = gridDim.x * 256;
  for (int i = blockIdx.x * 256 + threadIdx.x; i < n4; i += stride) {
    int4 d = d4[i];
    atomicAdd(&h[d.x >> PSHIFT], 1);
    atomicAdd(&h[d.y >> PSHIFT], 1);
    atomicAdd(&h[d.z >> PSHIFT], 1);
    atomicAdd(&h[d.w >> PSHIFT], 1);
  }
  __syncthreads();
  for (int i = threadIdx.x; i < NPB; i += 256) {
    int v = h[i];
    if (v) atomicAdd(&gh[i], v);
  }
}

__global__ __launch_bounds__(256) void gscan_k(const int* __restrict__ gh,
                                               int* __restrict__ boff,
                                               int* __restrict__ gcur) {
  __shared__ int sa[256], sb[256];
  int t = threadIdx.x;
  int v = (t < NPB) ? gh[t] : 0;
  sa[t] = v;
  __syncthreads();
  int* src = sa; int* dst = sb;
  for (int o = 1; o < 256; o <<= 1) {
    dst[t] = src[t] + ((t >= o) ? src[t - o] : 0);
    __syncthreads();
    int* tmp = src; src = dst; dst = tmp;
  }
  if (t < NPB) {
    int excl = src[t] - v;
    boff[t] = excl;
    gcur[t] = excl;
    if (t == NPB - 1) boff[NPB] = src[t];
  }
}

__global__ __launch_bounds__(512) void part_k(const int* __restrict__ ei,
                                              int* __restrict__ gcur,
                                              unsigned* __restrict__ tmp) {
  __shared__ int lh[NPB];
  __shared__ int lcur[NPB];
  int t = threadIdx.x;
  for (int i = t; i < NPB; i += 512) lh[i] = 0;
  __syncthreads();
  int q0 = blockIdx.x * (CHUNK_E / 4);
  int q1 = q0 + CHUNK_E / 4;
  const int4* d4 = (const int4*)(ei + N_EDGES);
  const int4* s4 = (const int4*)ei;
  for (int i = q0 + t; i < q1; i += 512) {
    int4 d = d4[i];
    atomicAdd(&lh[d.x >> PSHIFT], 1);
    atomicAdd(&lh[d.y >> PSHIFT], 1);
    atomicAdd(&lh[d.z >> PSHIFT], 1);
    atomicAdd(&lh[d.w >> PSHIFT], 1);
  }
  __syncthreads();
  for (int i = t; i < NPB; i += 512) {
    int v = lh[i];
    lcur[i] = v ? atomicAdd(&gcur[i], v) : 0;
  }
  __syncthreads();
  for (int i = q0 + t; i < q1; i += 512) {
    int4 d = d4[i];
    int4 s = s4[i];
    int b0 = d.x >> PSHIFT, b1 = d.y >> PSHIFT, b2 = d.z >> PSHIFT, b3 = d.w >> PSHIFT;
    int p0 = atomicAdd(&lcur[b0], 1);
    int p1 = atomicAdd(&lcur[b1], 1);
    int p2 = atomicAdd(&lcur[b2], 1);
    int p3 = atomicAdd(&lcur[b3], 1);
    tmp[p0] = ((unsigned)(d.x & (PBS - 1)) << 17) | (unsigned)s.x;
    tmp[p1] = ((unsigned)(d.y & (PBS - 1)) << 17) | (unsigned)s.y;
    tmp[p2] = ((unsigned)(d.z & (PBS - 1)) << 17) | (unsigned)s.z;
    tmp[p3] = ((unsigned)(d.w & (PBS - 1)) << 17) | (unsigned)s.w;
  }
}

// fused per-bucket: histogram per (node, src-quartile) -> rp4/dinv -> place
__global__ __launch_bounds__(512) void bwork_k(
    const unsigned* __restrict__ tmp, const int* __restrict__ boff,
    int* __restrict__ rp4, float* __restrict__ dinv, int* __restrict__ csr) {
  int b = blockIdx.x;
  int base = boff[b], end = boff[b + 1];
  int t = threadIdx.x;
  __shared__ int cnt[PBS * 4];
  __shared__ int cur[PBS * 4];
  __shared__ int sa[PBS], sb[PBS];
  for (int i = t; i < PBS * 4; i += 512) cnt[i] = 0;
  __syncthreads();
  int a0 = (base + 3) & ~3;
  int a1 = end & ~3;
  if (a1 < a0) { a0 = end; a1 = end; }
  const uint4* t4 = (const uint4*)tmp;
#define HIST1(U) { unsigned u_ = (U); int nl_ = u_ >> 17; int s_ = u_ & 0x1FFFF; \
    int qq_ = (s_ >= QBOUND) + (s_ >= 2*QBOUND) + (s_ >= 3*QBOUND); \
    atomicAdd(&cnt[nl_ * 4 + qq_], 1); }
  if (base + t < a0) HIST1(tmp[base + t]);
  for (int i = a0 / 4 + t; i < a1 / 4; i += 512) {
    uint4 u = t4[i];
    HIST1(u.x) HIST1(u.y) HIST1(u.z) HIST1(u.w)
  }
  if (a1 + t < end) HIST1(tmp[a1 + t]);
#undef HIST1
  __syncthreads();
  int c0 = cnt[t * 4], c1 = cnt[t * 4 + 1], c2 = cnt[t * 4 + 2], c3 = cnt[t * 4 + 3];
  int tsum = c0 + c1 + c2 + c3;
  sa[t] = tsum;
  __syncthreads();
  int* src_ = sa; int* dst_ = sb;
  for (int o = 1; o < PBS; o <<= 1) {
    dst_[t] = src_[t] + ((t >= o) ? src_[t - o] : 0);
    __syncthreads();
    int* z = src_; src_ = dst_; dst_ = z;
  }
  int nb = src_[t] - tsum;
  int o0 = nb, o1 = nb + c0, o2 = nb + c0 + c1, o3 = nb + c0 + c1 + c2;
  cur[t * 4] = o0; cur[t * 4 + 1] = o1; cur[t * 4 + 2] = o2; cur[t * 4 + 3] = o3;
  int n = b * PBS + t;
  if (n < N_NODES) {
    rp4[4 * n] = base + o0;
    rp4[4 * n + 1] = base + o1;
    rp4[4 * n + 2] = base + o2;
    rp4[4 * n + 3] = base + o3;
    dinv[n] = rsqrtf((float)(tsum + 1));  // +1 self loop
    if (n == N_NODES - 1) rp4[4 * N_NODES] = base + nb + tsum;
  }
  __syncthreads();
#define PLACE1(U) { unsigned u_ = (U); int nl_ = u_ >> 17; int s_ = u_ & 0x1FFFF; \
    int qq_ = (s_ >= QBOUND) + (s_ >= 2*QBOUND) + (s_ >= 3*QBOUND); \
    int p_ = atomicAdd(&cur[nl_ * 4 + qq_], 1); \
    csr[base + p_] = s_ << 7; }
  if (base + t < a0) PLACE1(tmp[base + t]);
  for (int i = a0 / 4 + t; i < a1 / 4; i += 512) {
    uint4 u = t4[i];
    PLACE1(u.x) PLACE1(u.y) PLACE1(u.z) PLACE1(u.w)
  }
  if (a1 + t < end) PLACE1(tmp[a1 + t]);
#undef PLACE1
}

// ---------------- MFMA GEMM: hs[n][c] = dinv[n] * (BN(X)[n] @ W)[c] -> bf16 ----------------

template <int K, bool XBF16, bool APPLY, bool RELU>
__global__ __launch_bounds__(256) void gemm_k(
    const void* __restrict__ Xv, const float* __restrict__ W,
    const float* __restrict__ sums, const float* __restrict__ gamma,
    const float* __restrict__ beta, const float* __restrict__ dinv,
    ushort_t* __restrict__ out, int nrows) {
  __shared__ ushort_t wt[64 * K];   // wt[n][k] bf16
  __shared__ float scs[128], shs[128];
  __shared__ float redo[64 * 65];   // D repack, padded
  const int tid = threadIdx.x;
  const int wv = tid >> 6;
  const int lane = tid & 63;
  const int lm = lane & 15;
  const int lq = lane >> 4;

  for (int idx = tid; idx < K * 64; idx += 256) {
    int k = idx >> 6, c = idx & 63;      // W[k][c]
    wt[c * K + k] = (ushort_t)f2bf(W[idx]);
  }
  if (APPLY) {
    for (int k = tid; k < K; k += 256) {
      float m = sums[k] / (float)N_NODES;
      float v = sums[64 + k] / (float)N_NODES - m * m;
      float s = gamma[k] * rsqrtf(v + BN_EPS);
      scs[k] = s;
      shs[k] = beta[k] - m * s;
    }
  }
  __syncthreads();

  const int rowbase = blockIdx.x * 64;
  const int grow = rowbase + wv * 16 + lm;
  const bool valid = grow < nrows;
  f32x4 acc0 = {0.f, 0.f, 0.f, 0.f};
  f32x4 acc1 = acc0, acc2 = acc0, acc3 = acc0;

#pragma unroll
  for (int k0 = 0; k0 < K; k0 += 32) {
    int kbase = k0 + lq * 8;
    bf16x8 a = {0, 0, 0, 0, 0, 0, 0, 0};
    if (valid) {
      if (XBF16) {
        uint4 u = *(const uint4*)((const char*)Xv + ((size_t)grow * 64 + kbase) * 2);
        if (APPLY) {
          float4 sc0 = *(const float4*)&scs[kbase];
          float4 sc1 = *(const float4*)&scs[kbase + 4];
          float4 sh0 = *(const float4*)&shs[kbase];
          float4 sh1 = *(const float4*)&shs[kbase + 4];
          float f0 = bflo(u.x) * sc0.x + sh0.x, f1 = bfhi(u.x) * sc0.y + sh0.y;
          float f2 = bflo(u.y) * sc0.z + sh0.z, f3 = bfhi(u.y) * sc0.w + sh0.w;
          float f4 = bflo(u.z) * sc1.x + sh1.x, f5 = bfhi(u.z) * sc1.y + sh1.y;
          float f6 = bflo(u.w) * sc1.z + sh1.z, f7 = bfhi(u.w) * sc1.w + sh1.w;
          if (RELU) {
            f0 = fmaxf(f0, 0.f); f1 = fmaxf(f1, 0.f);
            f2 = fmaxf(f2, 0.f); f3 = fmaxf(f3, 0.f);
            f4 = fmaxf(f4, 0.f); f5 = fmaxf(f5, 0.f);
            f6 = fmaxf(f6, 0.f); f7 = fmaxf(f7, 0.f);
          }
          a[0] = (short)f2bf(f0); a[1] = (short)f2bf(f1);
          a[2] = (short)f2bf(f2); a[3] = (short)f2bf(f3);
          a[4] = (short)f2bf(f4); a[5] = (short)f2bf(f5);
          a[6] = (short)f2bf(f6); a[7] = (short)f2bf(f7);
        } else {
          a = *(const bf16x8*)&u;
        }
      } else {
        const float* xp = (const float*)Xv + (size_t)grow * K + kbase;
        float4 xa = *(const float4*)xp;
        float4 xb = *(const float4*)(xp + 4);
        a[0] = (short)f2bf(xa.x); a[1] = (short)f2bf(xa.y);
        a[2] = (short)f2bf(xa.z); a[3] = (short)f2bf(xa.w);
        a[4] = (short)f2bf(xb.x); a[5] = (short)f2bf(xb.y);
        a[6] = (short)f2bf(xb.z); a[7] = (short)f2bf(xb.w);
      }
    }
    bf16x8 b0 = *(const bf16x8*)(wt + (0 + lm) * K + kbase);
    bf16x8 b1 = *(const bf16x8*)(wt + (16 + lm) * K + kbase);
    bf16x8 b2 = *(const bf16x8*)(wt + (32 + lm) * K + kbase);
    bf16x8 b3 = *(const bf16x8*)(wt + (48 + lm) * K + kbase);
    acc0 = __builtin_amdgcn_mfma_f32_16x16x32_bf16(a, b0, acc0, 0, 0, 0);
    acc1 = __builtin_amdgcn_mfma_f32_16x16x32_bf16(a, b1, acc1, 0, 0, 0);
    acc2 = __builtin_amdgcn_mfma_f32_16x16x32_bf16(a, b2, acc2, 0, 0, 0);
    acc3 = __builtin_amdgcn_mfma_f32_16x16x32_bf16(a, b3, acc3, 0, 0, 0);
  }

#pragma unroll
  for (int r = 0; r < 4; ++r) {
    int rr = wv * 16 + lq * 4 + r;
    redo[rr * 65 + lm] = acc0[r];
    redo[rr * 65 + 16 + lm] = acc1[r];
    redo[rr * 65 + 32 + lm] = acc2[r];
    redo[rr * 65 + 48 + lm] = acc3[r];
  }
  __syncthreads();
  {
    int r = tid >> 2;
    int cq = (tid & 3) * 16;
    int gr = rowbase + r;
    if (gr < nrows) {
      float dn = dinv[gr];
      const float* sp = &redo[r * 65 + cq];
      unsigned p[8];
#pragma unroll
      for (int i = 0; i < 8; ++i)
        p[i] = f2bf(sp[2 * i] * dn) | (f2bf(sp[2 * i + 1] * dn) << 16);
      char* ob = (char*)out + ((size_t)gr * 64 + cq) * 2;
      *(uint4*)ob = make_uint4(p[0], p[1], p[2], p[3]);
      *(uint4*)(ob + 16) = make_uint4(p[4], p[5], p[6], p[7]);
    }
  }
}

// ---------------- aggregation: unphased, 16-lane x uint2 rows, 4-node interleave, DEPTH-16 ----------------
// r7 (this geometry at depth-8) broke the 88-us plateau to 76 us -> the
// service rate does respond to per-wave outstanding depth in the uint2
// granularity (r6's depth null was in the inferior uint4 granularity).
// This round doubles depth: lookahead 4 per node x 4 nodes = 16 uint2
// gathers in flight per wave (256 cachelines), csr prefetch one batch
// ahead unchanged. Dead slots rise (iters = ceil(max/4)) but sentinel
// slots are near-free L1 hits. VGPR headroom: 48 -> ~90, no cliff.
// POOL=true (layer 3): skip the out-write, fuse raw graph pooling via
// block LDS; BN3 affine in classify_k.

template <bool POOL>
__global__ __launch_bounds__(256) void agg_k(
    const ushort_t* __restrict__ hs, const float* __restrict__ dinv,
    const int* __restrict__ rp4, const int* __restrict__ csr,
    const float* __restrict__ bias, ushort_t* __restrict__ out,
    float* __restrict__ sums, const int* __restrict__ batch,
    float* __restrict__ psum, float* __restrict__ pcnt) {
  const int tid = threadIdx.x;
  const int w = tid >> 6;
  const int lane = tid & 63;
  const int g = lane >> 4;     // node-group slot within wave
  const int q = lane & 15;     // feature quad
  const char* hb = (const char*)hs;
  char* ob = (char*)out;
  const int qo = q << 3;

  __shared__ float rs[16][64];
  __shared__ float rs2[16][64];
  __shared__ float pl[POOL ? 64 * 64 : 1];
  __shared__ float pcl[POOL ? 64 : 1];
  if (POOL) {
    for (int i = tid; i < 64 * 64; i += 256) pl[i] = 0.f;
    if (tid < 64) pcl[tid] = 0.f;
    __syncthreads();
  }

  const int nb = blockIdx.x * 64 + (w * 4 + g) * 4;  // first of 4 nodes

  int j0 = 0, h0 = 0, j1 = 0, h1 = 0, j2 = 0, h2 = 0, j3 = 0, h3 = 0;
  if (nb < N_NODES)     { j0 = rp4[4 * nb];           h0 = rp4[4 * nb + 4]; }
  if (nb + 1 < N_NODES) { j1 = rp4[4 * (nb + 1)];     h1 = rp4[4 * (nb + 1) + 4]; }
  if (nb + 2 < N_NODES) { j2 = rp4[4 * (nb + 2)];     h2 = rp4[4 * (nb + 2) + 4]; }
  if (nb + 3 < N_NODES) { j3 = rp4[4 * (nb + 3)];     h3 = rp4[4 * (nb + 3) + 4]; }

  float4 bval = *(const float4*)(bias + q * 4);
  float4 acc0 = make_float4(0.f, 0.f, 0.f, 0.f);
  float4 acc1 = acc0, acc2 = acc0, acc3 = acc0;

#define ACCV(A, V) { \
    A.x += bflo((V).x); A.y += bfhi((V).x); A.z += bflo((V).y); A.w += bfhi((V).y); }
// sentinel-selected csr fetch: in-bounds -> csr[j]; OOB -> zeroed row offset
#define EFETCH(J, H) ((J) < (H) ? csr[(J)] : (int)SENT_OFF)

  {
    int mrem = max(max(h0 - j0, h1 - j1), max(h2 - j2, h3 - j3));
    int iters = (mrem + 3) >> 2;
    if (iters > 0) {
      // prologue: first csr batch (OOB slots -> sentinel row)
      int e00 = EFETCH(j0, h0), e01 = EFETCH(j0 + 1, h0);
      int e02 = EFETCH(j0 + 2, h0), e03 = EFETCH(j0 + 3, h0);
      int e10 = EFETCH(j1, h1), e11 = EFETCH(j1 + 1, h1);
      int e12 = EFETCH(j1 + 2, h1), e13 = EFETCH(j1 + 3, h1);
      int e20 = EFETCH(j2, h2), e21 = EFETCH(j2 + 1, h2);
      int e22 = EFETCH(j2 + 2, h2), e23 = EFETCH(j2 + 3, h2);
      int e30 = EFETCH(j3, h3), e31 = EFETCH(j3 + 1, h3);
      int e32 = EFETCH(j3 + 2, h3), e33 = EFETCH(j3 + 3, h3);
      for (int it = 0; it < iters; ++it) {
        // 16 gathers in flight (256 cachelines per wave)
        uint2 v00 = *(const uint2*)(hb + (size_t)(unsigned)e00 + qo);
        uint2 v01 = *(const uint2*)(hb + (size_t)(unsigned)e01 + qo);
        uint2 v02 = *(const uint2*)(hb + (size_t)(unsigned)e02 + qo);
        uint2 v03 = *(const uint2*)(hb + (size_t)(unsigned)e03 + qo);
        uint2 v10 = *(const uint2*)(hb + (size_t)(unsigned)e10 + qo);
        uint2 v11 = *(const uint2*)(hb + (size_t)(unsigned)e11 + qo);
        uint2 v12 = *(const uint2*)(hb + (size_t)(unsigned)e12 + qo);
        uint2 v13 = *(const uint2*)(hb + (size_t)(unsigned)e13 + qo);
        uint2 v20 = *(const uint2*)(hb + (size_t)(unsigned)e20 + qo);
        uint2 v21 = *(const uint2*)(hb + (size_t)(unsigned)e21 + qo);
        uint2 v22 = *(const uint2*)(hb + (size_t)(unsigned)e22 + qo);
        uint2 v23 = *(const uint2*)(hb + (size_t)(unsigned)e23 + qo);
        uint2 v30 = *(const uint2*)(hb + (size_t)(unsigned)e30 + qo);
        uint2 v31 = *(const uint2*)(hb + (size_t)(unsigned)e31 + qo);
        uint2 v32 = *(const uint2*)(hb + (size_t)(unsigned)e32 + qo);
        uint2 v33 = *(const uint2*)(hb + (size_t)(unsigned)e33 + qo);
        j0 += 4; j1 += 4; j2 += 4; j3 += 4;
        // prefetch next csr batch while gathers are in flight
        e00 = EFETCH(j0, h0); e01 = EFETCH(j0 + 1, h0);
        e02 = EFETCH(j0 + 2, h0); e03 = EFETCH(j0 + 3, h0);
        e10 = EFETCH(j1, h1); e11 = EFETCH(j1 + 1, h1);
        e12 = EFETCH(j1 + 2, h1); e13 = EFETCH(j1 + 3, h1);
        e20 = EFETCH(j2, h2); e21 = EFETCH(j2 + 1, h2);
        e22 = EFETCH(j2 + 2, h2); e23 = EFETCH(j2 + 3, h2);
        e30 = EFETCH(j3, h3); e31 = EFETCH(j3 + 1, h3);
        e32 = EFETCH(j3 + 2, h3); e33 = EFETCH(j3 + 3, h3);
        // accumulate (sentinel contributes exact +0.0)
        ACCV(acc0, v00) ACCV(acc0, v01) ACCV(acc0, v02) ACCV(acc0, v03)
        ACCV(acc1, v10) ACCV(acc1, v11) ACCV(acc1, v12) ACCV(acc1, v13)
        ACCV(acc2, v20) ACCV(acc2, v21) ACCV(acc2, v22) ACCV(acc2, v23)
        ACCV(acc3, v30) ACCV(acc3, v31) ACCV(acc3, v32) ACCV(acc3, v33)
      }
    }
  }
#undef ACCV
#undef EFETCH

  float4 s = make_float4(0.f, 0.f, 0.f, 0.f);
  float4 s2 = make_float4(0.f, 0.f, 0.f, 0.f);
  int curg = -1, pcount = 0;
  float4 pacc = make_float4(0.f, 0.f, 0.f, 0.f);
#pragma unroll
  for (int i = 0; i < 4; ++i) {
    int n = nb + i;
    if (n < N_NODES) {
      float4 ai = (i == 0) ? acc0 : (i == 1) ? acc1 : (i == 2) ? acc2 : acc3;
      uint2 su = *(const uint2*)(hb + ((size_t)n << 7) + qo);
      float dn = dinv[n];
      float4 a;
      a.x = (ai.x + bflo(su.x)) * dn + bval.x;
      a.y = (ai.y + bfhi(su.x)) * dn + bval.y;
      a.z = (ai.z + bflo(su.y)) * dn + bval.z;
      a.w = (ai.w + bfhi(su.y)) * dn + bval.w;
      if (!POOL) {
        uint2 o;
        o.x = f2bf(a.x) | (f2bf(a.y) << 16);
        o.y = f2bf(a.z) | (f2bf(a.w) << 16);
        *(uint2*)(ob + ((size_t)n << 7) + qo) = o;
      } else {
        int gi = batch[n];  // uniform across the 16-lane group
        if (gi != curg) {
          if (pcount) {
            atomicAdd(&pl[curg * 64 + (q << 2)], pacc.x);
            atomicAdd(&pl[curg * 64 + (q << 2) + 1], pacc.y);
            atomicAdd(&pl[curg * 64 + (q << 2) + 2], pacc.z);
            atomicAdd(&pl[curg * 64 + (q << 2) + 3], pacc.w);
            if (q == 0) atomicAdd(&pcl[curg], (float)pcount);
          }
          curg = gi;
          pacc = a;
          pcount = 1;
        } else {
          pacc.x += a.x; pacc.y += a.y; pacc.z += a.z; pacc.w += a.w;
          pcount++;
        }
      }
      s.x += a.x; s.y += a.y; s.z += a.z; s.w += a.w;
      s2.x += a.x * a.x; s2.y += a.y * a.y;
      s2.z += a.z * a.z; s2.w += a.w * a.w;
    }
  }
  if (POOL && pcount) {
    atomicAdd(&pl[curg * 64 + (q << 2)], pacc.x);
    atomicAdd(&pl[curg * 64 + (q << 2) + 1], pacc.y);
    atomicAdd(&pl[curg * 64 + (q << 2) + 2], pacc.z);
    atomicAdd(&pl[curg * 64 + (q << 2) + 3], pacc.w);
    if (q == 0) atomicAdd(&pcl[curg], (float)pcount);
  }

  *(float4*)(&rs[w * 4 + g][q * 4]) = s;
  *(float4*)(&rs2[w * 4 + g][q * 4]) = s2;
  __syncthreads();
  int c = tid & 63;
  int r0_ = tid >> 6;
  float a = rs[r0_][c] + rs[r0_ + 4][c] + rs[r0_ + 8][c] + rs[r0_ + 12][c];
  float a2 = rs2[r0_][c] + rs2[r0_ + 4][c] + rs2[r0_ + 8][c] + rs2[r0_ + 12][c];
  __syncthreads();
  rs[r0_][c] = a;
  rs2[r0_][c] = a2;
  __syncthreads();
  if (r0_ == 0) {
    atomicAdd(&sums[c], rs[0][c] + rs[1][c] + rs[2][c] + rs[3][c]);
    atomicAdd(&sums[64 + c], rs2[0][c] + rs2[1][c] + rs2[2][c] + rs2[3][c]);
  }
  if (POOL) {
    for (int idx = tid; idx < 64 * 64; idx += 256) {
      int gi = idx >> 6;
      if (pcl[gi] != 0.f) atomicAdd(&psum[idx], pl[idx]);
    }
    if (tid < 64 && pcl[tid] != 0.f) atomicAdd(&pcnt[tid], pcl[tid]);
  }
}

// ---------------- centroid classifier (BN3 affine applied here) ----------------

__global__ void classify_k(const float* __restrict__ psum, const float* __restrict__ pcnt,
                           const float* __restrict__ sums, const float* __restrict__ gamma,
                           const float* __restrict__ beta,
                           const float* __restrict__ cg_, const float* __restrict__ cm,
                           const float* __restrict__ temp, float* __restrict__ out) {
  int g = blockIdx.x;
  int t = threadIdx.x;
  __shared__ float emb[64];
  __shared__ float dist[208];
  if (t < 64) {
    float m = sums[t] / (float)N_NODES;
    float v = sums[64 + t] / (float)N_NODES - m * m;
    float sc = gamma[t] * rsqrtf(v + BN_EPS);
    float sh = beta[t] - m * sc;
    // mean(BN(a)) = sc*mean(a) + sh  (affine commutes with the mean)
    emb[t] = psum[g * 64 + t] / fmaxf(pcnt[g], 1.0f) * sc + sh;
  }
  __syncthreads();
  if (t < 197) {
    const float* C = (t < 5) ? (cg_ + t * 64) : (cm + (t - 5) * 64);
    float d = 0.f;
#pragma unroll 8
    for (int k = 0; k < 64; ++k) {
      float df = emb[k] - C[k];
      d += df * df;
    }
    dist[t] = d;
  }
  __syncthreads();
  float tv = temp[0];
  if (t == 64) {
    float m = dist[0];
    for (int j = 1; j < 5; ++j) m = fminf(m, dist[j]);
    out[g * 65] = -m / tv;
  }
  if (t < 64) {
    float m = fminf(dist[5 + t * 3], fminf(dist[5 + t * 3 + 1], dist[5 + t * 3 + 2]));
    out[g * 65 + 1 + t] = -m / tv;
  }
}

// ---------------- launch ----------------

extern "C" void kernel_launch(void* const* d_in, const int* in_sizes, int n_in,
                              void* d_out, int out_size, void* d_ws, size_t ws_size,
                              hipStream_t stream) {
  const float* x   = (const float*)d_in[0];
  const int* ei    = (const int*)d_in[1];
  const int* batch = (const int*)d_in[2];
  const float* W1 = (const float*)d_in[3];  const float* b1 = (const float*)d_in[4];
  const float* g1 = (const float*)d_in[5];  const float* be1 = (const float*)d_in[6];
  const float* W2 = (const float*)d_in[7];  const float* b2 = (const float*)d_in[8];
  const float* g2 = (const float*)d_in[9];  const float* be2 = (const float*)d_in[10];
  const float* W3 = (const float*)d_in[11]; const float* b3 = (const float*)d_in[12];
  const float* g3 = (const float*)d_in[13]; const float* be3 = (const float*)d_in[14];
  const float* cg_ = (const float*)d_in[15];
  const float* cm = (const float*)d_in[16];
  const float* temp = (const float*)d_in[17];
  float* out = (float*)d_out;

  char* ws = (char*)d_ws;
  size_t off = 0;
  auto alloc = [&](size_t bytes) -> void* {
    void* p = ws + off;
    off = (off + bytes + 255) & ~(size_t)255;
    return p;
  };
  // zero-init block first -> single memset
  int* gh        = (int*)alloc((size_t)NPB * 4);
  float* sumsAll = (float*)alloc(3 * 128 * 4);
  float* psum    = (float*)alloc(64 * 64 * 4);
  float* pcnt    = (float*)alloc(64 * 4);
  size_t zero_end = off;
  int* boff      = (int*)alloc((size_t)(NPB + 1) * 4);
  int* gcur      = (int*)alloc((size_t)NPB * 4);
  unsigned* tmp  = (unsigned*)alloc((size_t)N_EDGES * 4);
  int* csr       = (int*)alloc((size_t)N_EDGES * 4);
  int* rp4       = (int*)alloc((size_t)(4 * N_NODES + 1) * 4);
  float* dinv    = (float*)alloc((size_t)N_NODES * 4);
  ushort_t* hA   = (ushort_t*)alloc((size_t)(N_NODES + 1) * 64 * 2);  // bf16 hs + sentinel row
  ushort_t* hB   = (ushort_t*)alloc((size_t)N_NODES * 64 * 2);        // bf16 h (pre-BN)

  hipMemsetAsync(ws, 0, zero_end, stream);
  hipMemsetAsync(hA + (size_t)N_NODES * 64, 0, 128, stream);  // zero sentinel row

  const int NB_GEMM = (N_NODES + 63) / 64;   // 1563

  // CSR build
  ghist_k<<<512, 256, 0, stream>>>(ei, gh);
  gscan_k<<<1, 256, 0, stream>>>(gh, boff, gcur);
  part_k<<<PART_BLOCKS, 512, 0, stream>>>(ei, gcur, tmp);
  bwork_k<<<NPB, 512, 0, stream>>>(tmp, boff, rp4, dinv, csr);

  // layer 1 (MFMA, fp32 X -> bf16 frags)
  gemm_k<IN_DIM, false, false, false><<<NB_GEMM, 256, 0, stream>>>(x, W1, nullptr, nullptr, nullptr, dinv, hA, N_NODES);
  agg_k<false><<<NB_AGG, 256, 0, stream>>>(hA, dinv, rp4, csr, b1, hB, sumsAll, nullptr, nullptr, nullptr);

  // layer 2 (BN1+ReLU inline from sums, bf16 input)
  gemm_k<HID, true, true, true><<<NB_GEMM, 256, 0, stream>>>(hB, W2, sumsAll, g1, be1, dinv, hA, N_NODES);
  agg_k<false><<<NB_AGG, 256, 0, stream>>>(hA, dinv, rp4, csr, b2, hB, sumsAll + 128, nullptr, nullptr, nullptr);

  // layer 3 (BN2+ReLU inline from sums, bf16 input); agg fuses raw pooling
  gemm_k<HID, true, true, true><<<NB_GEMM, 256, 0, stream>>>(hB, W3, sumsAll + 128, g2, be2, dinv, hA, N_NODES);
  agg_k<true><<<NB_AGG, 256, 0, stream>>>(hA, dinv, rp4, csr, b3, nullptr, sumsAll + 256, batch, psum, pcnt);

  // classify (BN3 affine inline from sums)
  classify_k<<<N_GRAPHS, 256, 0, stream>>>(psum, pcnt, sumsAll + 256, g3, be3, cg_, cm, temp, out);
}